// Round 9
// baseline (265.915 us; speedup 1.0000x reference)
//
#include <hip/hip_runtime.h>
#include <math.h>

// Problem constants
#define QN 4096
#define MN 65536
#define DN 384
#define CN 128
#define NCHUNK 64                 // m-chunks
#define MROWS_PER_CHUNK (MN / NCHUNK)   // 1024
#define MT_PER (MROWS_PER_CHUNK / 64)   // 16 m-tiles (64 rows) per block
#define BTILE_B (64 * DN)               // 24576 B per B tile (global layout)
#define PIECE_B (16 * DN)               // 6144 B: one 16-row piece (1 MFMA B-op x 3kc)
#define NPBUF 3                         // private piece-buffers per wave
#define WBUF_B (NPBUF * PIECE_B)        // 18432 B per wave

typedef __attribute__((ext_vector_type(8))) int i32x8;
typedef __attribute__((ext_vector_type(4))) int i32x4;
typedef __attribute__((ext_vector_type(4))) float f32x4;

__device__ __forceinline__ void async16(const void* g, void* l) {
  __builtin_amdgcn_global_load_lds(
      (const __attribute__((address_space(1))) unsigned int*)g,
      (__attribute__((address_space(3))) unsigned int*)l, 16, 0, 0);
}

// ------- Kernel A: L2-normalize rows (q then m) -> fp8, one wave per row ---
// Vectorized (G13): float2 loads, cvt_pk_fp8 paired ushort stores.
__global__ __launch_bounds__(256) void nrm_kernel(const float* __restrict__ qe,
                                                  const float* __restrict__ me,
                                                  unsigned char* __restrict__ yq,
                                                  unsigned char* __restrict__ ym) {
  const int row = blockIdx.x * 4 + (threadIdx.x >> 6);
  const int lane = threadIdx.x & 63;
  const float* xr;
  unsigned char* yr;
  if (row < QN) {
    xr = qe + (size_t)row * DN;
    yr = yq + (size_t)row * DN;
  } else {
    xr = me + (size_t)(row - QN) * DN;
    yr = ym + (size_t)(row - QN) * DN;
  }
  float2 v[3];
  float ss = 0.f;
#pragma unroll
  for (int i = 0; i < 3; ++i) {
    v[i] = *(const float2*)&xr[lane * 2 + i * 128];
    ss += v[i].x * v[i].x + v[i].y * v[i].y;
  }
#pragma unroll
  for (int m = 1; m < 64; m <<= 1) ss += __shfl_xor(ss, m);
  const float scale = 1.0f / fmaxf(sqrtf(ss), 1e-8f);
  unsigned short* yw = (unsigned short*)yr;
#pragma unroll
  for (int i = 0; i < 3; ++i) {
    const int p = __builtin_amdgcn_cvt_pk_fp8_f32(v[i].x * scale,
                                                  v[i].y * scale, 0, false);
    yw[lane + i * 64] = (unsigned short)(p & 0xffff);
  }
}

// ------- Kernel B: MX-fp8 GEMM, BARRIER-FREE per-wave private pipeline -----
// R9: R5-R8 proved the wall is block-level barrier lockstep (LDS ~100k +
// matrix ~106k cyc/CU run as a SUM = 218k = 91 µs). Barriers exist only
// because waves share staged B. Remove the sharing: each wave stages its OWN
// 32-row B slice into a private LDS region (wr-duplication moves to L2 reads
// — L2-resident per R1 — and LDS writes). Main loop has ZERO s_barriers; the
// 8 waves/CU drift freely so ds_reads of one wave overlap MFMAs of another.
// Piece pipeline (piece = 16 rows = one MFMA B-operand x 3 kc, 32 pieces):
//   p: vmcnt(6)  [p+1 landed, p+2 in flight]
//      6 ds_reads of p+1 -> other reg set (reg dbuf: net 0 VGPR vs R5)
//      lgkmcnt(6) [p's reads drained; 6 newest = p+1's, different buf]
//      stage p+3 into p's buffer (just drained -> no WAR)
//      12 MFMAs on regs read LAST iteration -> no wait precedes them.
// 3 private buffers/wave = 18,432 B; total LDS 74,752 -> 2 blocks/CU.
__global__ __launch_bounds__(256, 2) void gemm_max_kernel(
    const unsigned char* __restrict__ qn8, const unsigned char* __restrict__ mn8,
    float* __restrict__ pmax) {
  __shared__ unsigned char Bs[4 * WBUF_B];  // 73,728 B (A staged here first)
  __shared__ float smax[2][128];

  const int tid = threadIdx.x;
  const int wave = tid >> 6, lane = tid & 63;
  const int wr = wave >> 1, wc = wave & 1;   // waves: 2x2 over 128q x 64m
  const int quad = lane >> 4, l16 = lane & 15;
  const int r7 = l16 & 7;

  // --- XCD-partitioned bijective swizzle (HW assigns XCD = linear id % 8) ---
  const int bid = blockIdx.y * gridDim.x + blockIdx.x;  // linear dispatch id
  const int xcd = bid & 7;
  const int j = bid >> 3;                    // 0..255 within this XCD
  const int ychunk = (xcd << 3) | (j >> 5);  // 8 m-chunks per XCD
  const int qrow0 = (j & 31) * 128;          // x sweeps fastest
  const int mchunk0 = ychunk * MROWS_PER_CHUNK;

  float rmax[16];
#pragma unroll
  for (int i = 0; i < 16; ++i) rmax[i] = -3.0e38f;

  // ---- stage A tile (128x384 = 48 KB) once, hoist fragments to registers --
  {
    const unsigned char* abase = qn8 + (size_t)qrow0 * DN;
#pragma unroll
    for (int i = 0; i < 12; ++i) {
      const int ci = i * 256 + tid;               // 16B chunk 0..3071
      const int row = ci / 24;
      const int jj = ci - row * 24;
      const int gj = (jj & 24) | ((jj ^ row) & 7);  // XOR-swizzled source chunk
      async16(abase + row * DN + gj * 16, &Bs[(i * 256 + wave * 64) * 16]);
    }
  }
  __syncthreads();  // full drain: A staged
  i32x8 afr[3][4];
#pragma unroll
  for (int kc = 0; kc < 3; ++kc)
#pragma unroll
    for (int rt = 0; rt < 4; ++rt) {
      const unsigned char* p = &Bs[(wr * 64 + rt * 16 + l16) * DN];
      i32x4 lo = *(const i32x4*)&p[(kc * 8 + ((quad * 2 + 0) ^ r7)) * 16];
      i32x4 hi = *(const i32x4*)&p[(kc * 8 + ((quad * 2 + 1) ^ r7)) * 16];
      afr[kc][rt][0] = lo[0]; afr[kc][rt][1] = lo[1];
      afr[kc][rt][2] = lo[2]; afr[kc][rt][3] = lo[3];
      afr[kc][rt][4] = hi[0]; afr[kc][rt][5] = hi[1];
      afr[kc][rt][6] = hi[2]; afr[kc][rt][7] = hi[3];
    }
  __syncthreads();  // all waves' afr reads done; LDS free for private staging

  // per-wave staging offsets: 6 issues per 16-row piece (384 chunks of 16B)
  int srcw[6];
#pragma unroll
  for (int i = 0; i < 6; ++i) {
    const int ci = i * 64 + lane;                 // 0..383
    const int row = ci / 24;                      // 0..15
    const int jj = ci - row * 24;
    const int gj = (jj & 24) | ((jj ^ row) & 7);  // row&7 == (ct*16+row)&7
    srcw[i] = row * DN + gj * 16;
  }
  const unsigned char* bwave = mn8 + (size_t)(mchunk0 + wc * 32) * DN;
  unsigned char* wbuf = &Bs[wave * WBUF_B];

  // prologue: stage pieces 0,1,2 into private bufs 0,1,2 (18 loads in flight)
#pragma unroll
  for (int q = 0; q < 3; ++q) {
    const unsigned char* pb =
        bwave + (size_t)(q >> 1) * BTILE_B + (size_t)(q & 1) * PIECE_B;
#pragma unroll
    for (int i = 0; i < 6; ++i)
      async16(pb + srcw[i], wbuf + q * PIECE_B + i * 1024);
  }

  asm volatile("s_waitcnt vmcnt(12)" ::: "memory");  // piece 0 landed (mine)
  __builtin_amdgcn_sched_barrier(0);

  i32x8 bfrA[3], bfrB[3];
  // pre-loop: read piece 0 -> bfrA
#pragma unroll
  for (int kc = 0; kc < 3; ++kc) {
    const unsigned char* pp = wbuf;  // piece buf 0
    i32x4 lo =
        *(const i32x4*)&pp[l16 * DN + (kc * 8 + ((quad * 2 + 0) ^ r7)) * 16];
    i32x4 hi =
        *(const i32x4*)&pp[l16 * DN + (kc * 8 + ((quad * 2 + 1) ^ r7)) * 16];
    bfrA[kc][0] = lo[0]; bfrA[kc][1] = lo[1];
    bfrA[kc][2] = lo[2]; bfrA[kc][3] = lo[3];
    bfrA[kc][4] = hi[0]; bfrA[kc][5] = hi[1];
    bfrA[kc][6] = hi[2]; bfrA[kc][7] = hi[3];
  }

  int b0 = 0;  // private buf index of current piece p (p % 3)

// Body for piece P: CUR holds P's fragments (read last iter); read P+1 into
// NXT; drain P's reads; restage buf b0 with piece P+3; MFMA on CUR.
#define PIECE_BODY(P, CUR, NXT)                                                \
  do {                                                                         \
    const int p_ = (P);                                                        \
    const int rb_ = (b0 == 2) ? 0 : b0 + 1; /* buf of piece p+1 */             \
    if (p_ < 31) {                                                             \
      if (p_ < 30)                                                             \
        asm volatile("s_waitcnt vmcnt(6)" ::: "memory");                       \
      else                                                                     \
        asm volatile("s_waitcnt vmcnt(0)" ::: "memory");                       \
      __builtin_amdgcn_sched_barrier(0);                                       \
      const unsigned char* pp = wbuf + rb_ * PIECE_B;                          \
      _Pragma("unroll") for (int kc = 0; kc < 3; ++kc) {                       \
        i32x4 lo = *(const i32x4*)&pp[l16 * DN +                               \
                                      (kc * 8 + ((quad * 2 + 0) ^ r7)) * 16];  \
        i32x4 hi = *(const i32x4*)&pp[l16 * DN +                               \
                                      (kc * 8 + ((quad * 2 + 1) ^ r7)) * 16];  \
        NXT[kc][0] = lo[0]; NXT[kc][1] = lo[1];                                \
        NXT[kc][2] = lo[2]; NXT[kc][3] = lo[3];                                \
        NXT[kc][4] = hi[0]; NXT[kc][5] = hi[1];                                \
        NXT[kc][6] = hi[2]; NXT[kc][7] = hi[3];                                \
      }                                                                        \
      asm volatile("s_waitcnt lgkmcnt(6)" ::: "memory");                       \
    } else {                                                                   \
      asm volatile("s_waitcnt lgkmcnt(0)" ::: "memory");                       \
    }                                                                          \
    __builtin_amdgcn_sched_barrier(0);                                         \
    if (p_ + 3 < 32) {                                                         \
      const int q_ = p_ + 3;                                                   \
      const unsigned char* nb = bwave + (size_t)(q_ >> 1) * BTILE_B +          \
                                (size_t)(q_ & 1) * PIECE_B;                    \
      unsigned char* dst = wbuf + b0 * PIECE_B;                                \
      _Pragma("unroll") for (int i = 0; i < 6; ++i)                            \
          async16(nb + srcw[i], dst + i * 1024);                               \
    }                                                                          \
    f32x4 acc[4];                                                              \
    _Pragma("unroll") for (int rt = 0; rt < 4; ++rt)                           \
        acc[rt] = (f32x4){0.f, 0.f, 0.f, 0.f};                                 \
    __builtin_amdgcn_s_setprio(1);                                             \
    _Pragma("unroll") for (int kc = 0; kc < 3; ++kc)                           \
        _Pragma("unroll") for (int rt = 0; rt < 4; ++rt)                       \
            acc[rt] = __builtin_amdgcn_mfma_scale_f32_16x16x128_f8f6f4(        \
                afr[kc][rt], CUR[kc], acc[rt], 0, 0, 0, 0x7f7f7f7f, 0,         \
                0x7f7f7f7f);                                                   \
    __builtin_amdgcn_s_setprio(0);                                             \
    _Pragma("unroll") for (int rt = 0; rt < 4; ++rt)                           \
        _Pragma("unroll") for (int r = 0; r < 4; ++r)                          \
            rmax[rt * 4 + r] = fmaxf(rmax[rt * 4 + r], acc[rt][r]);            \
    b0 = rb_;                                                                  \
  } while (0)

#pragma unroll 1
  for (int pp2 = 0; pp2 < 32; pp2 += 2) {
    PIECE_BODY(pp2, bfrA, bfrB);
    PIECE_BODY(pp2 + 1, bfrB, bfrA);
  }
#undef PIECE_BODY

#pragma unroll
  for (int i = 0; i < 16; ++i) {
    float v = rmax[i];
    v = fmaxf(v, __shfl_xor(v, 1));
    v = fmaxf(v, __shfl_xor(v, 2));
    v = fmaxf(v, __shfl_xor(v, 4));
    v = fmaxf(v, __shfl_xor(v, 8));
    rmax[i] = v;
  }
  if (l16 == 0) {
#pragma unroll
    for (int rt = 0; rt < 4; ++rt)
#pragma unroll
      for (int r = 0; r < 4; ++r)
        smax[wc][wr * 64 + rt * 16 + quad * 4 + r] = rmax[rt * 4 + r];
  }
  __syncthreads();
  if (tid < 128) {
    const float v = fmaxf(smax[0][tid], smax[1][tid]);
    pmax[(size_t)(qrow0 + tid) * NCHUNK + ychunk] = v;
  }
}

// ------- Kernel C: reduce partials; uniform row OR exact fp32 re-check -----
__global__ __launch_bounds__(256) void decide_kernel(
    const float* __restrict__ pmax, const float* __restrict__ qe,
    const float* __restrict__ me, const float* __restrict__ labels,
    float* __restrict__ out) {
  const int q = blockIdx.x;
  const int t = threadIdx.x;  // 256
  __shared__ float smx;
  if (t < 64) {
    float v = pmax[(size_t)q * NCHUNK + t];  // NCHUNK == 64
#pragma unroll
    for (int m = 1; m < 64; m <<= 1) v = fmaxf(v, __shfl_xor(v, m));
    if (t == 0) smx = v;
  }
  __syncthreads();
  if (smx <= 0.5f) {  // uniform fast path (expected for all queries)
    if (t < CN) out[(size_t)q * CN + t] = 1.0f / 128.0f;
    return;
  }
  // exact fp32 path (rare / borderline queries only)
  __shared__ float sred[256];
  __shared__ int sidx[256];
  __shared__ float wsum[4];
  const float* qr = qe + (size_t)q * DN;
  float ss = 0.f;
  for (int i = t; i < DN; i += 256) ss += qr[i] * qr[i];
#pragma unroll
  for (int m = 1; m < 64; m <<= 1) ss += __shfl_xor(ss, m);
  if ((t & 63) == 0) wsum[t >> 6] = ss;
  __syncthreads();
  const float qnorm = fmaxf(sqrtf(wsum[0] + wsum[1] + wsum[2] + wsum[3]), 1e-8f);

  float best = -3.0e38f;
  int bidx = 0x7fffffff;
  for (int j = t; j < MN; j += 256) {
    const float* mr = me + (size_t)j * DN;
    float dot = 0.f, ms = 0.f;
    for (int k = 0; k < DN; ++k) {
      float a = qr[k], b = mr[k];
      dot += a * b;
      ms += b * b;
    }
    const float sim = dot / (qnorm * fmaxf(sqrtf(ms), 1e-8f));
    if (sim > best) { best = sim; bidx = j; }  // strict > keeps first index
  }
  sred[t] = best;
  sidx[t] = bidx;
  __syncthreads();
  for (int s = 128; s > 0; s >>= 1) {
    if (t < s) {
      const float ov = sred[t + s];
      const int oi = sidx[t + s];
      if (ov > sred[t] || (ov == sred[t] && oi < sidx[t])) {
        sred[t] = ov;
        sidx[t] = oi;
      }
    }
    __syncthreads();
  }
  const float mx = sred[0];
  const int mi = sidx[0];
  if (t < CN)
    out[(size_t)q * CN + t] =
        (mx > 0.7f) ? labels[(size_t)mi * CN + t] : (1.0f / 128.0f);
}

extern "C" void kernel_launch(void* const* d_in, const int* in_sizes, int n_in,
                              void* d_out, int out_size, void* d_ws,
                              size_t ws_size, hipStream_t stream) {
  const float* qe = (const float*)d_in[0];  // [4096,384] f32
  const float* me = (const float*)d_in[1];  // [65536,384] f32
  const float* lb = (const float*)d_in[2];  // [65536,128] f32
  float* out = (float*)d_out;               // [4096,128] f32

  char* ws = (char*)d_ws;
  const size_t OFF_QN = 0;
  const size_t OFF_MN = OFF_QN + (size_t)QN * DN;        // 1,572,864
  const size_t OFF_PMAX = OFF_MN + (size_t)MN * DN;      // +25,165,824
  unsigned char* qn8 = (unsigned char*)(ws + OFF_QN);
  unsigned char* mn8 = (unsigned char*)(ws + OFF_MN);
  float* pmax = (float*)(ws + OFF_PMAX);                 // [4096][64] = 1 MB

  nrm_kernel<<<(QN + MN) / 4, 256, 0, stream>>>(qe, me, qn8, mn8);
  gemm_max_kernel<<<dim3(QN / 128, NCHUNK), 256, 0, stream>>>(qn8, mn8, pmax);
  decide_kernel<<<QN, 256, 0, stream>>>(pmax, qe, me, lb, out);
}

// Round 10
// 245.340 us; speedup vs baseline: 1.0839x; 1.0839x over previous
//
#include <hip/hip_runtime.h>
#include <math.h>

// Problem constants
#define QN 4096
#define MN 65536
#define DN 384
#define CN 128
#define NCHUNK 64                 // m-chunks
#define MROWS_PER_CHUNK (MN / NCHUNK)   // 1024
#define MT_PER (MROWS_PER_CHUNK / 64)   // 16 m-tiles (64 rows) per block
#define BTILE_B (64 * DN)               // 24576 B per B tile
#define NBUF 2                          // 2 buffers, 50,176 B LDS

typedef __attribute__((ext_vector_type(8))) int i32x8;
typedef __attribute__((ext_vector_type(4))) int i32x4;
typedef __attribute__((ext_vector_type(4))) float f32x4;

__device__ __forceinline__ void async16(const void* g, void* l) {
  __builtin_amdgcn_global_load_lds(
      (const __attribute__((address_space(1))) unsigned int*)g,
      (__attribute__((address_space(3))) unsigned int*)l, 16, 0, 0);
}

// ------- Kernel A: L2-normalize rows (q then m) -> fp8, one wave per row ---
// Vectorized (G13): float2 loads, cvt_pk_fp8 paired ushort stores.
__global__ __launch_bounds__(256) void nrm_kernel(const float* __restrict__ qe,
                                                  const float* __restrict__ me,
                                                  unsigned char* __restrict__ yq,
                                                  unsigned char* __restrict__ ym) {
  const int row = blockIdx.x * 4 + (threadIdx.x >> 6);
  const int lane = threadIdx.x & 63;
  const float* xr;
  unsigned char* yr;
  if (row < QN) {
    xr = qe + (size_t)row * DN;
    yr = yq + (size_t)row * DN;
  } else {
    xr = me + (size_t)(row - QN) * DN;
    yr = ym + (size_t)(row - QN) * DN;
  }
  float2 v[3];
  float ss = 0.f;
#pragma unroll
  for (int i = 0; i < 3; ++i) {
    v[i] = *(const float2*)&xr[lane * 2 + i * 128];
    ss += v[i].x * v[i].x + v[i].y * v[i].y;
  }
#pragma unroll
  for (int m = 1; m < 64; m <<= 1) ss += __shfl_xor(ss, m);
  const float scale = 1.0f / fmaxf(sqrtf(ss), 1e-8f);
  unsigned short* yw = (unsigned short*)yr;
#pragma unroll
  for (int i = 0; i < 3; ++i) {
    const int p = __builtin_amdgcn_cvt_pk_fp8_f32(v[i].x * scale,
                                                  v[i].y * scale, 0, false);
    yw[lane + i * 64] = (unsigned short)(p & 0xffff);
  }
}

// ------- Kernel B: MX-fp8 GEMM, R8 schedule + anti-phase stagger -----------
// R10: R8 verbatim (best: 91.1 µs) + ONE change: a half-period s_sleep for
// one parity of co-resident block pairs. R5-R9 model: per CU, 2 blocks run
// identical periods (read-phase 1536 contended + MFMA 828 + slop ~= 3400cyc
// x 64 periods = 218k = 91 µs); phase ALIGNMENT is an attractor (lagging
// block gets uncontended LDS and catches up), so both pipes idle ~50%.
// Anti-phased: each block reads (768 uncontended) under the other's MFMA
// (828) -> period ~1600-2000 -> wall ~48-55 µs. s_sleep 13 (~832 cyc) at
// loop entry for parity ((bid^(bid>>8))&1) creates the offset; contention
// asymmetry then self-maintains it. Cost if wrong: 0.35 µs.
__global__ __launch_bounds__(256, 2) void gemm_max_kernel(
    const unsigned char* __restrict__ qn8, const unsigned char* __restrict__ mn8,
    float* __restrict__ pmax) {
  __shared__ unsigned char Bs[NBUF * BTILE_B];  // 48 KB (A staged here first)
  __shared__ float smax[2][128];

  const int tid = threadIdx.x;
  const int wave = tid >> 6, lane = tid & 63;
  const int wr = wave >> 1, wc = wave & 1;   // waves: 2x2 over 128q x 64m
  const int quad = lane >> 4, l16 = lane & 15;
  const int r7 = l16 & 7;

  // --- XCD-partitioned bijective swizzle (HW assigns XCD = linear id % 8) ---
  const int bid = blockIdx.y * gridDim.x + blockIdx.x;  // linear dispatch id
  const int xcd = bid & 7;
  const int j = bid >> 3;                    // 0..255 within this XCD
  const int ychunk = (xcd << 3) | (j >> 5);  // 8 m-chunks per XCD
  const int qrow0 = (j & 31) * 128;          // x sweeps fastest
  const int mchunk0 = ychunk * MROWS_PER_CHUNK;

  float rmax[16];
#pragma unroll
  for (int i = 0; i < 16; ++i) rmax[i] = -3.0e38f;

  // ---- stage A tile (128x384 = 48 KB) once, hoist fragments to registers --
  {
    const unsigned char* abase = qn8 + (size_t)qrow0 * DN;
#pragma unroll
    for (int i = 0; i < 12; ++i) {
      const int ci = i * 256 + tid;               // 16B chunk 0..3071
      const int row = ci / 24;
      const int jj = ci - row * 24;
      const int gj = (jj & 24) | ((jj ^ row) & 7);  // XOR-swizzled source chunk
      async16(abase + row * DN + gj * 16, &Bs[(i * 256 + wave * 64) * 16]);
    }
  }
  __syncthreads();  // full drain: A staged
  i32x8 afr[3][4];
#pragma unroll
  for (int kc = 0; kc < 3; ++kc)
#pragma unroll
    for (int rt = 0; rt < 4; ++rt) {
      const unsigned char* p = &Bs[(wr * 64 + rt * 16 + l16) * DN];
      i32x4 lo = *(const i32x4*)&p[(kc * 8 + ((quad * 2 + 0) ^ r7)) * 16];
      i32x4 hi = *(const i32x4*)&p[(kc * 8 + ((quad * 2 + 1) ^ r7)) * 16];
      afr[kc][rt][0] = lo[0]; afr[kc][rt][1] = lo[1];
      afr[kc][rt][2] = lo[2]; afr[kc][rt][3] = lo[3];
      afr[kc][rt][4] = hi[0]; afr[kc][rt][5] = hi[1];
      afr[kc][rt][6] = hi[2]; afr[kc][rt][7] = hi[3];
    }
  __syncthreads();  // afr reads done; LDS free for B staging

  // B staging source offsets: 6 issues/thread per 64-row tile (1536 chunks)
  int srcoff[6];
#pragma unroll
  for (int i = 0; i < 6; ++i) {
    const int ci = i * 256 + tid;                 // 16B chunk 0..1535
    const int row = ci / 24;
    const int jj = ci - row * 24;
    const int gj = (jj & 24) | ((jj ^ row) & 7);
    srcoff[i] = row * DN + gj * 16;
  }

  const unsigned char* bchunk = mn8 + (size_t)mchunk0 * DN;
  // depth-1 prologue: tile 0 -> buf 0 (6 loads in flight)
#pragma unroll
  for (int i = 0; i < 6; ++i)
    async16(bchunk + srcoff[i], &Bs[(i * 256 + wave * 64) * 16]);

  // ---- anti-phase stagger: half-period sleep for one co-resident parity ---
  if ((bid ^ (bid >> 8)) & 1) __builtin_amdgcn_s_sleep(13);  // ~832 cyc

#pragma unroll 1
  for (int mt = 0; mt < MT_PER; ++mt) {
    // all outstanding loads are tile mt's 6 (issued last iter / prologue)
    asm volatile("s_waitcnt vmcnt(0)" ::: "memory");
    __builtin_amdgcn_s_barrier();            // all waves: tile mt visible,
                                             // tile mt-1 reads complete
    __builtin_amdgcn_sched_barrier(0);       // keep reads below the barrier

    const unsigned char* cur = &Bs[(mt & 1) * BTILE_B];

    // 12 B-fragment ds_reads — NO manual lgkm pin; compiler interleaves
    // partial lgkmcnt waits with the MFMA cluster below.
    i32x8 bfr[3][2];
#pragma unroll
    for (int kc = 0; kc < 3; ++kc)
#pragma unroll
      for (int ct = 0; ct < 2; ++ct) {
        const unsigned char* p = &cur[(wc * 32 + ct * 16 + l16) * DN];
        i32x4 lo = *(const i32x4*)&p[(kc * 8 + ((quad * 2 + 0) ^ r7)) * 16];
        i32x4 hi = *(const i32x4*)&p[(kc * 8 + ((quad * 2 + 1) ^ r7)) * 16];
        bfr[kc][ct][0] = lo[0]; bfr[kc][ct][1] = lo[1];
        bfr[kc][ct][2] = lo[2]; bfr[kc][ct][3] = lo[3];
        bfr[kc][ct][4] = hi[0]; bfr[kc][ct][5] = hi[1];
        bfr[kc][ct][6] = hi[2]; bfr[kc][ct][7] = hi[3];
      }

    // stage tile mt+1 into buf (mt+1)&1 (safe: last read in iter mt-1,
    // all waves past the top barrier of this iter)
    if (mt + 1 < MT_PER) {
      unsigned char* dst = &Bs[((mt + 1) & 1) * BTILE_B];
      const unsigned char* nb = bchunk + (size_t)(mt + 1) * BTILE_B;
#pragma unroll
      for (int i = 0; i < 6; ++i)
        async16(nb + srcoff[i], &dst[(i * 256 + wave * 64) * 16]);
    }

    f32x4 acc[4][2];
#pragma unroll
    for (int rt = 0; rt < 4; ++rt)
#pragma unroll
      for (int ct = 0; ct < 2; ++ct) acc[rt][ct] = (f32x4){0.f, 0.f, 0.f, 0.f};

    __builtin_amdgcn_s_setprio(1);
#pragma unroll
    for (int kc = 0; kc < 3; ++kc)
#pragma unroll
      for (int rt = 0; rt < 4; ++rt)
#pragma unroll
        for (int ct = 0; ct < 2; ++ct)
          acc[rt][ct] = __builtin_amdgcn_mfma_scale_f32_16x16x128_f8f6f4(
              afr[kc][rt], bfr[kc][ct], acc[rt][ct], 0, 0,  // fmt fp8/fp8
              0, 0x7f7f7f7f, 0, 0x7f7f7f7f);                // scales = 1.0
    __builtin_amdgcn_s_setprio(0);

#pragma unroll
    for (int rt = 0; rt < 4; ++rt)
#pragma unroll
      for (int r = 0; r < 4; ++r) {
        const float v = fmaxf(acc[rt][0][r], acc[rt][1][r]);
        rmax[rt * 4 + r] = fmaxf(rmax[rt * 4 + r], v);
      }
  }

#pragma unroll
  for (int i = 0; i < 16; ++i) {
    float v = rmax[i];
    v = fmaxf(v, __shfl_xor(v, 1));
    v = fmaxf(v, __shfl_xor(v, 2));
    v = fmaxf(v, __shfl_xor(v, 4));
    v = fmaxf(v, __shfl_xor(v, 8));
    rmax[i] = v;
  }
  if (l16 == 0) {
#pragma unroll
    for (int rt = 0; rt < 4; ++rt)
#pragma unroll
      for (int r = 0; r < 4; ++r)
        smax[wc][wr * 64 + rt * 16 + quad * 4 + r] = rmax[rt * 4 + r];
  }
  __syncthreads();
  if (tid < 128) {
    const float v = fmaxf(smax[0][tid], smax[1][tid]);
    pmax[(size_t)(qrow0 + tid) * NCHUNK + ychunk] = v;
  }
}

// ------- Kernel C: reduce partials; uniform row OR exact fp32 re-check -----
__global__ __launch_bounds__(256) void decide_kernel(
    const float* __restrict__ pmax, const float* __restrict__ qe,
    const float* __restrict__ me, const float* __restrict__ labels,
    float* __restrict__ out) {
  const int q = blockIdx.x;
  const int t = threadIdx.x;  // 256
  __shared__ float smx;
  if (t < 64) {
    float v = pmax[(size_t)q * NCHUNK + t];  // NCHUNK == 64
#pragma unroll
    for (int m = 1; m < 64; m <<= 1) v = fmaxf(v, __shfl_xor(v, m));
    if (t == 0) smx = v;
  }
  __syncthreads();
  if (smx <= 0.5f) {  // uniform fast path (expected for all queries)
    if (t < CN) out[(size_t)q * CN + t] = 1.0f / 128.0f;
    return;
  }
  // exact fp32 path (rare / borderline queries only)
  __shared__ float sred[256];
  __shared__ int sidx[256];
  __shared__ float wsum[4];
  const float* qr = qe + (size_t)q * DN;
  float ss = 0.f;
  for (int i = t; i < DN; i += 256) ss += qr[i] * qr[i];
#pragma unroll
  for (int m = 1; m < 64; m <<= 1) ss += __shfl_xor(ss, m);
  if ((t & 63) == 0) wsum[t >> 6] = ss;
  __syncthreads();
  const float qnorm = fmaxf(sqrtf(wsum[0] + wsum[1] + wsum[2] + wsum[3]), 1e-8f);

  float best = -3.0e38f;
  int bidx = 0x7fffffff;
  for (int j = t; j < MN; j += 256) {
    const float* mr = me + (size_t)j * DN;
    float dot = 0.f, ms = 0.f;
    for (int k = 0; k < DN; ++k) {
      float a = qr[k], b = mr[k];
      dot += a * b;
      ms += b * b;
    }
    const float sim = dot / (qnorm * fmaxf(sqrtf(ms), 1e-8f));
    if (sim > best) { best = sim; bidx = j; }  // strict > keeps first index
  }
  sred[t] = best;
  sidx[t] = bidx;
  __syncthreads();
  for (int s = 128; s > 0; s >>= 1) {
    if (t < s) {
      const float ov = sred[t + s];
      const int oi = sidx[t + s];
      if (ov > sred[t] || (ov == sred[t] && oi < sidx[t])) {
        sred[t] = ov;
        sidx[t] = oi;
      }
    }
    __syncthreads();
  }
  const float mx = sred[0];
  const int mi = sidx[0];
  if (t < CN)
    out[(size_t)q * CN + t] =
        (mx > 0.7f) ? labels[(size_t)mi * CN + t] : (1.0f / 128.0f);
}

extern "C" void kernel_launch(void* const* d_in, const int* in_sizes, int n_in,
                              void* d_out, int out_size, void* d_ws,
                              size_t ws_size, hipStream_t stream) {
  const float* qe = (const float*)d_in[0];  // [4096,384] f32
  const float* me = (const float*)d_in[1];  // [65536,384] f32
  const float* lb = (const float*)d_in[2];  // [65536,128] f32
  float* out = (float*)d_out;               // [4096,128] f32

  char* ws = (char*)d_ws;
  const size_t OFF_QN = 0;
  const size_t OFF_MN = OFF_QN + (size_t)QN * DN;        // 1,572,864
  const size_t OFF_PMAX = OFF_MN + (size_t)MN * DN;      // +25,165,824
  unsigned char* qn8 = (unsigned char*)(ws + OFF_QN);
  unsigned char* mn8 = (unsigned char*)(ws + OFF_MN);
  float* pmax = (float*)(ws + OFF_PMAX);                 // [4096][64] = 1 MB

  nrm_kernel<<<(QN + MN) / 4, 256, 0, stream>>>(qe, me, qn8, mn8);
  gemm_max_kernel<<<dim3(QN / 128, NCHUNK), 256, 0, stream>>>(qn8, mn8, pmax);
  decide_kernel<<<QN, 256, 0, stream>>>(pmax, qe, me, lb, out);
}